// Round 3
// baseline (733.344 us; speedup 1.0000x reference)
//
#include <hip/hip_runtime.h>
#include <math.h>

// GAT 3-layer: N=50000 nodes, E=800000 edges (+N self loops), HEADS=2, HID=64.
// R3: split edge softmax into scalar phase (thread-per-dst: exp/max work once,
// not replicated across 64 lanes) + vector aggregate phase (wave-per-dst,
// ~6 instrs/edge: broadcast p + one b64 H load + 2 FMA). att reduce fused
// into gemm epilogue.

__device__ __forceinline__ float lrelu(float v) { return v > 0.f ? v : 0.2f * v; }

__global__ void init_kernel(int* __restrict__ deg, float* __restrict__ gsum,
                            int* __restrict__ gcnt, int n, int g) {
  int i = blockIdx.x * blockDim.x + threadIdx.x;
  if (i < n) deg[i] = 1;                 // self loop
  if (i < g) { gsum[i] = 0.f; gcnt[i] = 0; }
}

__global__ void count_kernel(const int* __restrict__ ei, int* __restrict__ deg, int e) {
  int i = blockIdx.x * blockDim.x + threadIdx.x;
  if (i < e) atomicAdd(&deg[ei[e + i]], 1);   // dst row of edge_index
}

// single-block exclusive scan (Hillis-Steele per 1024-chunk, serial carry)
__global__ void scan_kernel(const int* __restrict__ deg, int* __restrict__ row_ptr, int n) {
  __shared__ int sm[1024];
  __shared__ int carry;
  int tid = threadIdx.x;
  if (tid == 0) carry = 0;
  __syncthreads();
  for (int base = 0; base < n; base += 1024) {
    int i = base + tid;
    int v = (i < n) ? deg[i] : 0;
    sm[tid] = v;
    __syncthreads();
    for (int off = 1; off < 1024; off <<= 1) {
      int t = (tid >= off) ? sm[tid - off] : 0;
      __syncthreads();
      sm[tid] += t;
      __syncthreads();
    }
    int c = carry;
    if (i < n) row_ptr[i] = c + sm[tid] - v;   // exclusive
    int total = sm[1023];
    __syncthreads();
    if (tid == 0) carry = c + total;
    __syncthreads();
  }
  if (tid == 0) row_ptr[n] = carry;
}

__global__ void cursor_kernel(const int* __restrict__ row_ptr, int* __restrict__ cursor, int n) {
  int i = blockIdx.x * blockDim.x + threadIdx.x;
  if (i < n) cursor[i] = row_ptr[i];
}

__global__ void scatter_kernel(const int* __restrict__ ei, int* __restrict__ cursor,
                               int* __restrict__ csr_src, int n, int e) {
  int i = blockIdx.x * blockDim.x + threadIdx.x;
  if (i < n) {                               // self loop
    int p = atomicAdd(&cursor[i], 1);
    csr_src[p] = i;
  } else if (i < n + e) {
    int j = i - n;
    int s = ei[j];
    int d = ei[e + j];
    int p = atomicAdd(&cursor[d], 1);
    csr_src[p] = s;
  }
}

// Tiled gemm + fused attention reduce.
// 64-row x 128-col block, 256 threads. cgrp = tid&31 -> cols [cgrp*4,+4);
// rg = tid>>5 -> rows [rg*8,+8). X tile in LDS (pad K+1). W from global
// (L1-hot). Epilogue: a_src/a_dst per (row,head) via 16-lane shfl reduce
// (cgrp 0-15 = head0 cols, 16-31 = head1 cols; xor bits 0-3 stay in group).
template <int K>
__global__ __launch_bounds__(256) void gemm_att(const float* __restrict__ X,
                                                const float* __restrict__ W,
                                                const float* __restrict__ asw,
                                                const float* __restrict__ adw,
                                                float* __restrict__ H,
                                                float* __restrict__ a_src,
                                                float* __restrict__ a_dst, int N) {
  __shared__ float Xs[64 * (K + 1)];
  int tid = threadIdx.x;
  int row0 = blockIdx.x * 64;

  for (int idx = tid; idx < 64 * K; idx += 256) {
    int r = idx / K;
    int k = idx - r * K;
    int gr = row0 + r;
    if (gr >= N) gr = N - 1;          // clamp pad rows (stores are guarded)
    Xs[r * (K + 1) + k] = X[(size_t)gr * K + k];
  }
  __syncthreads();

  int cgrp = tid & 31;
  int c0 = cgrp * 4;
  int rg = tid >> 5;
  const float* wp = W + c0;
  float acc[8][4] = {};

#pragma unroll 4
  for (int k = 0; k < K; ++k) {
    float4 w4 = *(const float4*)(wp + k * 128);
#pragma unroll
    for (int j = 0; j < 8; ++j) {
      float xv = Xs[(rg * 8 + j) * (K + 1) + k];
      acc[j][0] = fmaf(xv, w4.x, acc[j][0]);
      acc[j][1] = fmaf(xv, w4.y, acc[j][1]);
      acc[j][2] = fmaf(xv, w4.z, acc[j][2]);
      acc[j][3] = fmaf(xv, w4.w, acc[j][3]);
    }
  }

  float4 aw = *(const float4*)(asw + c0);
  float4 dw = *(const float4*)(adw + c0);
#pragma unroll
  for (int j = 0; j < 8; ++j) {
    int r = row0 + rg * 8 + j;
    float sp = acc[j][0] * aw.x + acc[j][1] * aw.y + acc[j][2] * aw.z + acc[j][3] * aw.w;
    float dp = acc[j][0] * dw.x + acc[j][1] * dw.y + acc[j][2] * dw.z + acc[j][3] * dw.w;
#pragma unroll
    for (int off = 1; off < 16; off <<= 1) {
      sp += __shfl_xor(sp, off, 64);
      dp += __shfl_xor(dp, off, 64);
    }
    if (r < N) {
      float4 v = make_float4(acc[j][0], acc[j][1], acc[j][2], acc[j][3]);
      *(float4*)(H + (size_t)r * 128 + c0) = v;
      if ((cgrp & 15) == 0) {
        int head = cgrp >> 4;
        a_src[r * 2 + head] = sp;
        a_dst[r * 2 + head] = dp;
      }
    }
  }
}

// thread per dst node: exact two-pass softmax scalars over in-edges.
// pass1: gather a_src, leaky-relu, stash e per slot, track max.
// pass2: p = exp(e - m), sum, overwrite slot with p. invS = 1/max(s,eps).
__global__ void softmax_scalars(const float* __restrict__ a_src,
                                const float* __restrict__ a_dst,
                                const int* __restrict__ row_ptr,
                                const int* __restrict__ csr,
                                float2* __restrict__ pE,
                                float2* __restrict__ invS, int N) {
  int i = blockIdx.x * blockDim.x + threadIdx.x;
  if (i >= N) return;
  int beg = row_ptr[i], end = row_ptr[i + 1];
  float2 ad = ((const float2*)a_dst)[i];
  float m0 = -1e30f, m1 = -1e30f;
  for (int j = beg; j < end; ++j) {
    int s = csr[j];
    float2 as = ((const float2*)a_src)[s];
    float e0 = lrelu(as.x + ad.x);
    float e1 = lrelu(as.y + ad.y);
    pE[j] = make_float2(e0, e1);
    m0 = fmaxf(m0, e0);
    m1 = fmaxf(m1, e1);
  }
  float s0 = 0.f, s1 = 0.f;
  for (int j = beg; j < end; ++j) {
    float2 e = pE[j];
    float p0 = __expf(e.x - m0);
    float p1 = __expf(e.y - m1);
    s0 += p0;
    s1 += p1;
    pE[j] = make_float2(p0, p1);
  }
  invS[i] = make_float2(1.f / fmaxf(s0, 1e-16f), 1.f / fmaxf(s1, 1e-16f));
}

// wave per dst node. lane l holds H cols 2l,2l+1 (lanes 0-31 head0, 32-63
// head1). Per edge: broadcast csr + p, one b64 coalesced H load, 2 FMA.
// Head mean via shfl_xor 32; lanes 0-31 store float2.
__global__ __launch_bounds__(256) void aggregate(const float* __restrict__ H,
                                                 const float2* __restrict__ pE,
                                                 const float2* __restrict__ invS,
                                                 const float* __restrict__ bias,
                                                 const int* __restrict__ row_ptr,
                                                 const int* __restrict__ csr,
                                                 float* __restrict__ out, int N) {
  int wid = blockIdx.x * (blockDim.x >> 6) + (threadIdx.x >> 6);
  if (wid >= N) return;
  int lane = threadIdx.x & 63;
  int beg = row_ptr[wid], end = row_ptr[wid + 1];
  bool hi = lane >= 32;
  float ax = 0.f, ay = 0.f;
  for (int j = beg; j < end; ++j) {
    int src = csr[j];
    float2 p = pE[j];
    float pl = hi ? p.y : p.x;
    float2 h = *(const float2*)(H + (size_t)src * 128 + lane * 2);
    ax = fmaf(h.x, pl, ax);
    ay = fmaf(h.y, pl, ay);
  }
  float2 inv = invS[wid];
  float il = hi ? inv.y : inv.x;
  ax *= il;
  ay *= il;
  float ox = 0.5f * (ax + __shfl_xor(ax, 32, 64));
  float oy = 0.5f * (ay + __shfl_xor(ay, 32, 64));
  if (lane < 32) {
    int c = lane * 2;
    float v0 = ox + bias[c];
    float v1 = oy + bias[c + 1];
    v0 = v0 > 0.f ? v0 : 0.f;
    v1 = v1 > 0.f ? v1 : 0.f;
    *(float2*)(out + (size_t)wid * 64 + c) = make_float2(v0, v1);
  }
}

__device__ __forceinline__ float wave_sum(float v) {
  for (int off = 32; off; off >>= 1) v += __shfl_xor(v, off, 64);
  return v;
}

// per-node dot with lin_w (linear commutes past the mean), atomic per-graph
__global__ void pool_kernel(const float* __restrict__ X, const float* __restrict__ lw,
                            const int* __restrict__ batch, float* __restrict__ gsum,
                            int* __restrict__ gcnt, int N) {
  int wid = blockIdx.x * (blockDim.x >> 6) + (threadIdx.x >> 6);
  if (wid >= N) return;
  int lane = threadIdx.x & 63;
  float v = X[(size_t)wid * 64 + lane] * lw[lane];
  v = wave_sum(v);
  if (lane == 0) {
    int g = batch[wid];
    atomicAdd(&gsum[g], v);
    atomicAdd(&gcnt[g], 1);
  }
}

__global__ void finalize_kernel(const float* __restrict__ gsum, const int* __restrict__ gcnt,
                                const float* __restrict__ lb, float* __restrict__ out, int G) {
  int g = blockIdx.x * blockDim.x + threadIdx.x;
  if (g < G) out[g] = gsum[g] / fmaxf((float)gcnt[g], 1.f) + lb[0];
}

extern "C" void kernel_launch(void* const* d_in, const int* in_sizes, int n_in,
                              void* d_out, int out_size, void* d_ws, size_t ws_size,
                              hipStream_t stream) {
  const float* x   = (const float*)d_in[0];
  const int* ei    = (const int*)d_in[1];
  const int* batch = (const int*)d_in[2];
  const float* W1  = (const float*)d_in[3];
  const float* as1 = (const float*)d_in[4];
  const float* ad1 = (const float*)d_in[5];
  const float* b1  = (const float*)d_in[6];
  const float* W2  = (const float*)d_in[7];
  const float* as2 = (const float*)d_in[8];
  const float* ad2 = (const float*)d_in[9];
  const float* b2  = (const float*)d_in[10];
  const float* W3  = (const float*)d_in[11];
  const float* as3 = (const float*)d_in[12];
  const float* ad3 = (const float*)d_in[13];
  const float* b3  = (const float*)d_in[14];
  const float* lw  = (const float*)d_in[15];
  const float* lb  = (const float*)d_in[16];
  float* out = (float*)d_out;

  const int N = in_sizes[0] / 128;   // 50000
  const int E = in_sizes[1] / 2;     // 800000
  const int ET = N + E;              // with self loops
  const int G = out_size;            // 2500

  char* p = (char*)d_ws;
  auto take = [&](size_t bytes) {
    char* r = p;
    p += (bytes + 255) & ~(size_t)255;
    return r;
  };
  int* deg      = (int*)take((size_t)N * 4);
  int* row_ptr  = (int*)take((size_t)(N + 1) * 4);
  int* cursor   = (int*)take((size_t)N * 4);
  int* csr      = (int*)take((size_t)ET * 4);
  float* H      = (float*)take((size_t)N * 128 * 4);
  float* a_src  = (float*)take((size_t)N * 2 * 4);
  float* a_dst  = (float*)take((size_t)N * 2 * 4);
  float2* pE    = (float2*)take((size_t)ET * 8);
  float2* invS  = (float2*)take((size_t)N * 8);
  float* bufA   = (float*)take((size_t)N * 64 * 4);
  float* bufB   = (float*)take((size_t)N * 64 * 4);
  float* gsum   = (float*)take((size_t)G * 4);
  int* gcnt     = (int*)take((size_t)G * 4);
  (void)ws_size; (void)n_in;

  // ---- CSR build (dst-sorted, with self loops) ----
  init_kernel<<<(N + 255) / 256, 256, 0, stream>>>(deg, gsum, gcnt, N, G);
  count_kernel<<<(E + 255) / 256, 256, 0, stream>>>(ei, deg, E);
  scan_kernel<<<1, 1024, 0, stream>>>(deg, row_ptr, N);
  cursor_kernel<<<(N + 255) / 256, 256, 0, stream>>>(row_ptr, cursor, N);
  scatter_kernel<<<(ET + 255) / 256, 256, 0, stream>>>(ei, cursor, csr, N, E);

  const int gblk = (N + 63) / 64;
  const int tblk = (N + 255) / 256;
  const int wblk = (N + 3) / 4;

  // ---- layer 1 (K=128) ----
  gemm_att<128><<<gblk, 256, 0, stream>>>(x, W1, as1, ad1, H, a_src, a_dst, N);
  softmax_scalars<<<tblk, 256, 0, stream>>>(a_src, a_dst, row_ptr, csr, pE, invS, N);
  aggregate<<<wblk, 256, 0, stream>>>(H, pE, invS, b1, row_ptr, csr, bufA, N);
  // ---- layer 2 (K=64) ----
  gemm_att<64><<<gblk, 256, 0, stream>>>(bufA, W2, as2, ad2, H, a_src, a_dst, N);
  softmax_scalars<<<tblk, 256, 0, stream>>>(a_src, a_dst, row_ptr, csr, pE, invS, N);
  aggregate<<<wblk, 256, 0, stream>>>(H, pE, invS, b2, row_ptr, csr, bufB, N);
  // ---- layer 3 (K=64) ----
  gemm_att<64><<<gblk, 256, 0, stream>>>(bufB, W3, as3, ad3, H, a_src, a_dst, N);
  softmax_scalars<<<tblk, 256, 0, stream>>>(a_src, a_dst, row_ptr, csr, pE, invS, N);
  aggregate<<<wblk, 256, 0, stream>>>(H, pE, invS, b3, row_ptr, csr, bufA, N);

  // ---- pool + linear ----
  pool_kernel<<<wblk, 256, 0, stream>>>(bufA, lw, batch, gsum, gcnt, N);
  finalize_kernel<<<(G + 255) / 256, 256, 0, stream>>>(gsum, gcnt, lb, out, G);
}

// Round 4
// 585.948 us; speedup vs baseline: 1.2516x; 1.2516x over previous
//
#include <hip/hip_runtime.h>
#include <math.h>

// GAT 3-layer: N=50000 nodes, E=800000 edges (+N self loops), HEADS=2, HID=64.
// R4: single fused aggregate per layer. Wave per dst: lane-parallel edge
// softmax (coalesced csr load, 64-wide a_src gather, shfl max/sum), then
// H-gather loop with register-broadcast src/p (no load-dependent addressing)
// so many 512B gathers stay in flight.

__device__ __forceinline__ float lrelu(float v) { return v > 0.f ? v : 0.2f * v; }

__device__ __forceinline__ float wave_sum(float v) {
  for (int off = 32; off; off >>= 1) v += __shfl_xor(v, off, 64);
  return v;
}
__device__ __forceinline__ float wave_max(float v) {
  for (int off = 32; off; off >>= 1) v = fmaxf(v, __shfl_xor(v, off, 64));
  return v;
}

__global__ void init_kernel(int* __restrict__ deg, float* __restrict__ gsum,
                            int* __restrict__ gcnt, int n, int g) {
  int i = blockIdx.x * blockDim.x + threadIdx.x;
  if (i < n) deg[i] = 1;                 // self loop
  if (i < g) { gsum[i] = 0.f; gcnt[i] = 0; }
}

__global__ void count_kernel(const int* __restrict__ ei, int* __restrict__ deg, int e) {
  int i = blockIdx.x * blockDim.x + threadIdx.x;
  if (i < e) atomicAdd(&deg[ei[e + i]], 1);   // dst row of edge_index
}

// single-block exclusive scan (Hillis-Steele per 1024-chunk, serial carry)
__global__ void scan_kernel(const int* __restrict__ deg, int* __restrict__ row_ptr, int n) {
  __shared__ int sm[1024];
  __shared__ int carry;
  int tid = threadIdx.x;
  if (tid == 0) carry = 0;
  __syncthreads();
  for (int base = 0; base < n; base += 1024) {
    int i = base + tid;
    int v = (i < n) ? deg[i] : 0;
    sm[tid] = v;
    __syncthreads();
    for (int off = 1; off < 1024; off <<= 1) {
      int t = (tid >= off) ? sm[tid - off] : 0;
      __syncthreads();
      sm[tid] += t;
      __syncthreads();
    }
    int c = carry;
    if (i < n) row_ptr[i] = c + sm[tid] - v;   // exclusive
    int total = sm[1023];
    __syncthreads();
    if (tid == 0) carry = c + total;
    __syncthreads();
  }
  if (tid == 0) row_ptr[n] = carry;
}

__global__ void cursor_kernel(const int* __restrict__ row_ptr, int* __restrict__ cursor, int n) {
  int i = blockIdx.x * blockDim.x + threadIdx.x;
  if (i < n) cursor[i] = row_ptr[i];
}

__global__ void scatter_kernel(const int* __restrict__ ei, int* __restrict__ cursor,
                               int* __restrict__ csr_src, int n, int e) {
  int i = blockIdx.x * blockDim.x + threadIdx.x;
  if (i < n) {                               // self loop
    int p = atomicAdd(&cursor[i], 1);
    csr_src[p] = i;
  } else if (i < n + e) {
    int j = i - n;
    int s = ei[j];
    int d = ei[e + j];
    int p = atomicAdd(&cursor[d], 1);
    csr_src[p] = s;
  }
}

// Tiled gemm + fused attention reduce.
// 64-row x 128-col block, 256 threads. cgrp = tid&31 -> cols [cgrp*4,+4);
// rg = tid>>5 -> rows [rg*8,+8). X tile in LDS (pad K+1). W from global
// (L1-hot). Epilogue: a_src/a_dst per (row,head) via 16-lane shfl reduce.
template <int K>
__global__ __launch_bounds__(256) void gemm_att(const float* __restrict__ X,
                                                const float* __restrict__ W,
                                                const float* __restrict__ asw,
                                                const float* __restrict__ adw,
                                                float* __restrict__ H,
                                                float* __restrict__ a_src,
                                                float* __restrict__ a_dst, int N) {
  __shared__ float Xs[64 * (K + 1)];
  int tid = threadIdx.x;
  int row0 = blockIdx.x * 64;

  for (int idx = tid; idx < 64 * K; idx += 256) {
    int r = idx / K;
    int k = idx - r * K;
    int gr = row0 + r;
    if (gr >= N) gr = N - 1;          // clamp pad rows (stores are guarded)
    Xs[r * (K + 1) + k] = X[(size_t)gr * K + k];
  }
  __syncthreads();

  int cgrp = tid & 31;
  int c0 = cgrp * 4;
  int rg = tid >> 5;
  const float* wp = W + c0;
  float acc[8][4] = {};

#pragma unroll 4
  for (int k = 0; k < K; ++k) {
    float4 w4 = *(const float4*)(wp + k * 128);
#pragma unroll
    for (int j = 0; j < 8; ++j) {
      float xv = Xs[(rg * 8 + j) * (K + 1) + k];
      acc[j][0] = fmaf(xv, w4.x, acc[j][0]);
      acc[j][1] = fmaf(xv, w4.y, acc[j][1]);
      acc[j][2] = fmaf(xv, w4.z, acc[j][2]);
      acc[j][3] = fmaf(xv, w4.w, acc[j][3]);
    }
  }

  float4 aw = *(const float4*)(asw + c0);
  float4 dw = *(const float4*)(adw + c0);
#pragma unroll
  for (int j = 0; j < 8; ++j) {
    int r = row0 + rg * 8 + j;
    float sp = acc[j][0] * aw.x + acc[j][1] * aw.y + acc[j][2] * aw.z + acc[j][3] * aw.w;
    float dp = acc[j][0] * dw.x + acc[j][1] * dw.y + acc[j][2] * dw.z + acc[j][3] * dw.w;
#pragma unroll
    for (int off = 1; off < 16; off <<= 1) {
      sp += __shfl_xor(sp, off, 64);
      dp += __shfl_xor(dp, off, 64);
    }
    if (r < N) {
      float4 v = make_float4(acc[j][0], acc[j][1], acc[j][2], acc[j][3]);
      *(float4*)(H + (size_t)r * 128 + c0) = v;
      if ((cgrp & 15) == 0) {
        int head = cgrp >> 4;
        a_src[r * 2 + head] = sp;
        a_dst[r * 2 + head] = dp;
      }
    }
  }
}

// Fused softmax + aggregate. Wave per dst node.
// Pass A (per 64-edge chunk): lane j loads csr[beg+j] coalesced + a_src[src]
// (64 parallel 8B gathers), e = lrelu, online wave max/sum. Chunk 0 (covers
// ~all nodes: avg deg 17) cached in registers for pass B.
// Pass B: p = exp(e-m) per lane; inner t-loop broadcasts (src,p) by shfl and
// gathers H rows (512B coalesced) with no load-dependent addressing.
__global__ __launch_bounds__(256) void aggregate_fused(
    const float* __restrict__ H, const float* __restrict__ a_src,
    const float* __restrict__ a_dst, const float* __restrict__ bias,
    const int* __restrict__ row_ptr, const int* __restrict__ csr,
    float* __restrict__ out, int N) {
  int wid = blockIdx.x * (blockDim.x >> 6) + (threadIdx.x >> 6);
  if (wid >= N) return;
  int lane = threadIdx.x & 63;
  bool hi = lane >= 32;
  int beg = row_ptr[wid], end = row_ptr[wid + 1];
  float2 ad = ((const float2*)a_dst)[wid];

  // ---- pass A: softmax stats (online across chunks) ----
  int src0 = 0;
  float e0c = -1e30f, e1c = -1e30f;
  float m0 = -1e30f, m1 = -1e30f, s0 = 0.f, s1 = 0.f;
  for (int base = beg; base < end; base += 64) {
    int j = base + lane;
    bool valid = j < end;
    int s = valid ? csr[j] : 0;
    float2 as = ((const float2*)a_src)[s];
    float e0 = lrelu(as.x + ad.x);
    float e1 = lrelu(as.y + ad.y);
    if (!valid) { e0 = -1e30f; e1 = -1e30f; }
    if (base == beg) { src0 = s; e0c = e0; e1c = e1; }
    float nm0 = fmaxf(m0, wave_max(e0));
    float nm1 = fmaxf(m1, wave_max(e1));
    s0 = s0 * __expf(m0 - nm0) + wave_sum(__expf(e0 - nm0));
    s1 = s1 * __expf(m1 - nm1) + wave_sum(__expf(e1 - nm1));
    m0 = nm0; m1 = nm1;
  }
  float inv0 = 1.f / fmaxf(s0, 1e-16f);
  float inv1 = 1.f / fmaxf(s1, 1e-16f);

  // ---- pass B: weighted gather ----
  float ax = 0.f, ay = 0.f;
  for (int base = beg; base < end; base += 64) {
    int s;
    float e0, e1;
    if (base == beg) {
      s = src0; e0 = e0c; e1 = e1c;
    } else {
      int j = base + lane;
      bool valid = j < end;
      s = valid ? csr[j] : 0;
      float2 as = ((const float2*)a_src)[s];
      e0 = valid ? lrelu(as.x + ad.x) : -1e30f;
      e1 = valid ? lrelu(as.y + ad.y) : -1e30f;
    }
    float p0 = __expf(e0 - m0);
    float p1 = __expf(e1 - m1);
    int cnt = end - base;
    if (cnt > 64) cnt = 64;
#pragma unroll 4
    for (int t = 0; t < cnt; ++t) {
      int st = __shfl(s, t, 64);
      float q0 = __shfl(p0, t, 64);
      float q1 = __shfl(p1, t, 64);
      float2 h = *(const float2*)(H + (size_t)st * 128 + (lane << 1));
      float pl = hi ? q1 : q0;
      ax = fmaf(h.x, pl, ax);
      ay = fmaf(h.y, pl, ay);
    }
  }
  float il = hi ? inv1 : inv0;
  ax *= il;
  ay *= il;
  float ox = 0.5f * (ax + __shfl_xor(ax, 32, 64));
  float oy = 0.5f * (ay + __shfl_xor(ay, 32, 64));
  if (lane < 32) {
    int c = lane * 2;
    float v0 = ox + bias[c];
    float v1 = oy + bias[c + 1];
    v0 = v0 > 0.f ? v0 : 0.f;
    v1 = v1 > 0.f ? v1 : 0.f;
    *(float2*)(out + (size_t)wid * 64 + c) = make_float2(v0, v1);
  }
}

// per-node dot with lin_w (linear commutes past the mean), atomic per-graph
__global__ void pool_kernel(const float* __restrict__ X, const float* __restrict__ lw,
                            const int* __restrict__ batch, float* __restrict__ gsum,
                            int* __restrict__ gcnt, int N) {
  int wid = blockIdx.x * (blockDim.x >> 6) + (threadIdx.x >> 6);
  if (wid >= N) return;
  int lane = threadIdx.x & 63;
  float v = X[(size_t)wid * 64 + lane] * lw[lane];
  v = wave_sum(v);
  if (lane == 0) {
    int g = batch[wid];
    atomicAdd(&gsum[g], v);
    atomicAdd(&gcnt[g], 1);
  }
}

__global__ void finalize_kernel(const float* __restrict__ gsum, const int* __restrict__ gcnt,
                                const float* __restrict__ lb, float* __restrict__ out, int G) {
  int g = blockIdx.x * blockDim.x + threadIdx.x;
  if (g < G) out[g] = gsum[g] / fmaxf((float)gcnt[g], 1.f) + lb[0];
}

extern "C" void kernel_launch(void* const* d_in, const int* in_sizes, int n_in,
                              void* d_out, int out_size, void* d_ws, size_t ws_size,
                              hipStream_t stream) {
  const float* x   = (const float*)d_in[0];
  const int* ei    = (const int*)d_in[1];
  const int* batch = (const int*)d_in[2];
  const float* W1  = (const float*)d_in[3];
  const float* as1 = (const float*)d_in[4];
  const float* ad1 = (const float*)d_in[5];
  const float* b1  = (const float*)d_in[6];
  const float* W2  = (const float*)d_in[7];
  const float* as2 = (const float*)d_in[8];
  const float* ad2 = (const float*)d_in[9];
  const float* b2  = (const float*)d_in[10];
  const float* W3  = (const float*)d_in[11];
  const float* as3 = (const float*)d_in[12];
  const float* ad3 = (const float*)d_in[13];
  const float* b3  = (const float*)d_in[14];
  const float* lw  = (const float*)d_in[15];
  const float* lb  = (const float*)d_in[16];
  float* out = (float*)d_out;

  const int N = in_sizes[0] / 128;   // 50000
  const int E = in_sizes[1] / 2;     // 800000
  const int ET = N + E;              // with self loops
  const int G = out_size;            // 2500

  char* p = (char*)d_ws;
  auto take = [&](size_t bytes) {
    char* r = p;
    p += (bytes + 255) & ~(size_t)255;
    return r;
  };
  int* deg      = (int*)take((size_t)N * 4);
  int* row_ptr  = (int*)take((size_t)(N + 1) * 4);
  int* cursor   = (int*)take((size_t)N * 4);
  int* csr      = (int*)take((size_t)ET * 4);
  float* H      = (float*)take((size_t)N * 128 * 4);
  float* a_src  = (float*)take((size_t)N * 2 * 4);
  float* a_dst  = (float*)take((size_t)N * 2 * 4);
  float* bufA   = (float*)take((size_t)N * 64 * 4);
  float* bufB   = (float*)take((size_t)N * 64 * 4);
  float* gsum   = (float*)take((size_t)G * 4);
  int* gcnt     = (int*)take((size_t)G * 4);
  (void)ws_size; (void)n_in;

  // ---- CSR build (dst-sorted, with self loops) ----
  init_kernel<<<(N + 255) / 256, 256, 0, stream>>>(deg, gsum, gcnt, N, G);
  count_kernel<<<(E + 255) / 256, 256, 0, stream>>>(ei, deg, E);
  scan_kernel<<<1, 1024, 0, stream>>>(deg, row_ptr, N);
  cursor_kernel<<<(N + 255) / 256, 256, 0, stream>>>(row_ptr, cursor, N);
  scatter_kernel<<<(ET + 255) / 256, 256, 0, stream>>>(ei, cursor, csr, N, E);

  const int gblk = (N + 63) / 64;
  const int wblk = (N + 3) / 4;

  // ---- layer 1 (K=128) ----
  gemm_att<128><<<gblk, 256, 0, stream>>>(x, W1, as1, ad1, H, a_src, a_dst, N);
  aggregate_fused<<<wblk, 256, 0, stream>>>(H, a_src, a_dst, b1, row_ptr, csr, bufA, N);
  // ---- layer 2 (K=64) ----
  gemm_att<64><<<gblk, 256, 0, stream>>>(bufA, W2, as2, ad2, H, a_src, a_dst, N);
  aggregate_fused<<<wblk, 256, 0, stream>>>(H, a_src, a_dst, b2, row_ptr, csr, bufB, N);
  // ---- layer 3 (K=64) ----
  gemm_att<64><<<gblk, 256, 0, stream>>>(bufB, W3, as3, ad3, H, a_src, a_dst, N);
  aggregate_fused<<<wblk, 256, 0, stream>>>(H, a_src, a_dst, b3, row_ptr, csr, bufA, N);

  // ---- pool + linear ----
  pool_kernel<<<wblk, 256, 0, stream>>>(bufA, lw, batch, gsum, gcnt, N);
  finalize_kernel<<<(G + 255) / 256, 256, 0, stream>>>(gsum, gcnt, lb, out, G);
}